// Round 7
// baseline (336.546 us; speedup 1.0000x reference)
//
#include <hip/hip_runtime.h>

// GraphiT-GT layer. B=32, N=128, D=64, H=8, DH=8.
// R7: HBM duty-cycle fix.
//  * score_kernel: streaming-only (e -> MFMA -> scores -> S[bf16] to ws).
//    Double-buffered LDS: row g+1's loads issued before row g's compute,
//    cvt+LDS-write after — loads stay in flight during MFMA/scores.
//    One barrier per row. S stored with fire-and-forget 8B stores.
//  * tail_kernel: 4096 one-wave blocks do attn/O-proj/LN1/FFN/LN2 from S.

#define NB 32
#define NN 128
#define ND 64
#define G 4

typedef __attribute__((ext_vector_type(8))) __bf16 bf16x8;
typedef __attribute__((ext_vector_type(8))) unsigned short u16x8;
typedef __attribute__((ext_vector_type(4))) float f32x4;

static __device__ __forceinline__ unsigned short f2bf(float x) {
  unsigned u = __float_as_uint(x);
  u += 0x7fffu + ((u >> 16) & 1u);   // RNE
  return (unsigned short)(u >> 16);
}
static __device__ __forceinline__ float bf2f(unsigned short u) {
  return __uint_as_float(((unsigned)u) << 16);
}

#define DPP_ADD(v, ctrl) \
  ((v) + __int_as_float(__builtin_amdgcn_update_dpp(0, __float_as_int(v), (ctrl), 0xf, 0xf, true)))

static __device__ __forceinline__ float wsum64(float v) {
  v += __shfl_xor(v, 1, 64);
  v += __shfl_xor(v, 2, 64);
  v += __shfl_xor(v, 4, 64);
  v += __shfl_xor(v, 8, 64);
  v += __shfl_xor(v, 16, 64);
  v += __shfl_xor(v, 32, 64);
  return v;
}

static __device__ __forceinline__ float4 xor_add4(float4 a, int m) {
  a.x += __shfl_xor(a.x, m, 64);
  a.y += __shfl_xor(a.y, m, 64);
  a.z += __shfl_xor(a.z, m, 64);
  a.w += __shfl_xor(a.w, m, 64);
  return a;
}

__global__ __launch_bounds__(64) void qkv_kernel(
    const float* __restrict__ h, const float* __restrict__ Wq,
    const float* __restrict__ Wk, const float* __restrict__ Wv,
    const float* __restrict__ We,
    float* __restrict__ Q, float* __restrict__ K, float* __restrict__ V,
    unsigned short* __restrict__ WeT) {
  if (blockIdx.x == NB * NN) {
    const int t = threadIdx.x;
#pragma unroll
    for (int k0 = 0; k0 < ND; k0 += 8) {
      u16x8 u;
#pragma unroll
      for (int j = 0; j < 8; ++j) u[j] = f2bf(We[(k0 + j) * ND + t]);
      *(u16x8*)(&WeT[t * ND + k0]) = u;
    }
    return;
  }
  const int r = blockIdx.x;       // r = b*128 + n
  const int t = threadIdx.x;
  __shared__ float hrow[ND];
  hrow[t] = h[(size_t)r * ND + t];
  __syncthreads();
  float q = 0.f, k = 0.f, v = 0.f;
#pragma unroll 8
  for (int d = 0; d < ND; ++d) {
    const float hv = hrow[d];
    q = fmaf(hv, Wq[d * ND + t], q);
    k = fmaf(hv, Wk[d * ND + t], k);
    v = fmaf(hv, Wv[d * ND + t], v);
  }
  Q[(size_t)r * ND + t] = q;
  K[(size_t)r * ND + t] = k * 0.35355339059327373f;  // DH^-0.5 folded in
  V[(size_t)r * ND + t] = v;
}

// ---------------- streaming kernel: E = e@We, scores -> Sws (bf16) ----------
__global__ __launch_bounds__(256, 4) void score_kernel(
    const float* __restrict__ e, const float* __restrict__ kRW,
    const float* __restrict__ Q, const float* __restrict__ K,
    const unsigned short* __restrict__ WeT,
    unsigned short* __restrict__ Sws) {
  const int blk = blockIdx.x;
  const int b = blk >> 5;
  const int i0 = (blk & 31) * G;
  const int tid = threadIdx.x;
  const int w = tid >> 6;
  const int L = tid & 63;
  const int quad = L >> 4;
  const int lrow = L & 15;

  __shared__ __align__(16) unsigned short e_lds[2][NN * 72];  // 2 x 18 KB
  __shared__ float q_lds[G * ND];
  __shared__ float krw_lds[G * NN];

  const size_t row0 = (size_t)b * NN + i0;
  const size_t kvbase = (size_t)b * NN * ND;

  q_lds[tid] = Q[row0 * ND + tid];
  krw_lds[tid] = kRW[row0 * NN + tid];
  krw_lds[256 + tid] = kRW[row0 * NN + 256 + tid];

  bf16x8 bfr[2][4];
#pragma unroll
  for (int ks = 0; ks < 2; ++ks)
#pragma unroll
    for (int n0 = 0; n0 < 4; ++n0)
      bfr[ks][n0] = __builtin_bit_cast(
          bf16x8, *(const u16x8*)(&WeT[(n0 * 16 + lrow) * ND + ks * 32 + quad * 8]));

  // K values this lane needs (reused for all G rows)
  float kreg[2][4][4];
#pragma unroll
  for (int mt = 0; mt < 2; ++mt)
#pragma unroll
    for (int n0 = 0; n0 < 4; ++n0)
#pragma unroll
      for (int reg = 0; reg < 4; ++reg)
        kreg[mt][n0][reg] =
            K[kvbase + (size_t)((w + mt * 4) * 16 + quad * 4 + reg) * ND + n0 * 16 + lrow];

  // stage row 0 into buffer 0
  float4 pf[8];
  {
    const float* ep = e + row0 * (size_t)(NN * ND);
#pragma unroll
    for (int p = 0; p < 8; ++p) pf[p] = *(const float4*)(ep + p * 1024 + tid * 4);
#pragma unroll
    for (int p = 0; p < 8; ++p) {
      const int idx = p * 1024 + tid * 4;
      *(ushort4*)(&e_lds[0][(idx >> 6) * 72 + (idx & 63)]) =
          make_ushort4(f2bf(pf[p].x), f2bf(pf[p].y), f2bf(pf[p].z), f2bf(pf[p].w));
    }
  }
  __syncthreads();

  for (int g = 0; g < G; ++g) {
    const int buf = g & 1;
    // 1) issue next row's loads (no wait — in flight during compute below)
    if (g + 1 < G) {
      const float* ep = e + (row0 + g + 1) * (size_t)(NN * ND);
#pragma unroll
      for (int p = 0; p < 8; ++p) pf[p] = *(const float4*)(ep + p * 1024 + tid * 4);
    }
    // 2) MFMA + scores for row g from e_lds[buf]
#pragma unroll
    for (int mt = 0; mt < 2; ++mt) {
      const int mr = w + mt * 4;
      bf16x8 afr[2];
#pragma unroll
      for (int ks = 0; ks < 2; ++ks)
        afr[ks] = __builtin_bit_cast(
            bf16x8, *(const u16x8*)(&e_lds[buf][(mr * 16 + lrow) * 72 + ks * 32 + quad * 8]));
      f32x4 acc[4];
#pragma unroll
      for (int n0 = 0; n0 < 4; ++n0) acc[n0] = (f32x4){0.f, 0.f, 0.f, 0.f};
#pragma unroll
      for (int ks = 0; ks < 2; ++ks)
#pragma unroll
        for (int n0 = 0; n0 < 4; ++n0)
          acc[n0] =
              __builtin_amdgcn_mfma_f32_16x16x32_bf16(afr[ks], bfr[ks][n0], acc[n0], 0, 0, 0);

      const float4 krw4 = *(const float4*)(&krw_lds[g * NN + mr * 16 + quad * 4]);
      const float* krwp = (const float*)&krw4;
#pragma unroll
      for (int n0 = 0; n0 < 4; ++n0) {
        const float qn = q_lds[g * ND + n0 * 16 + lrow];
        float sv[4];
#pragma unroll
        for (int reg = 0; reg < 4; ++reg) {
          float tv = acc[n0][reg] * qn * kreg[mt][n0][reg];
          tv = DPP_ADD(tv, 0xB1);   // quad_perm xor1
          tv = DPP_ADD(tv, 0x4E);   // quad_perm xor2
          tv = DPP_ADD(tv, 0x141);  // row_half_mirror (completes 8-lane head)
          sv[reg] = __expf(fminf(fmaxf(tv, -5.f), 5.f)) * krwp[reg];
        }
        if ((L & 7) == 0) {
          const int hh = n0 * 2 + ((L >> 3) & 1);
          // fire-and-forget 8B store: S[row][h][j] bf16
          *(ushort4*)(&Sws[((row0 + g) * 8 + hh) * NN + mr * 16 + quad * 4]) =
              make_ushort4(f2bf(sv[0]), f2bf(sv[1]), f2bf(sv[2]), f2bf(sv[3]));
        }
      }
    }
    // 3) convert + stage next row into the other buffer (vmcnt wait lands here)
    if (g + 1 < G) {
#pragma unroll
      for (int p = 0; p < 8; ++p) {
        const int idx = p * 1024 + tid * 4;
        *(ushort4*)(&e_lds[1 - buf][(idx >> 6) * 72 + (idx & 63)]) =
            make_ushort4(f2bf(pf[p].x), f2bf(pf[p].y), f2bf(pf[p].z), f2bf(pf[p].w));
      }
    }
    __syncthreads();
  }
}

// ---------------- tail kernel: attn -> O-proj -> LN1 -> FFN -> LN2 ----------
__global__ __launch_bounds__(64) void tail_kernel(
    const float* __restrict__ h, const unsigned short* __restrict__ Sws,
    const float* __restrict__ V,
    const float* __restrict__ Wo, const float* __restrict__ bo,
    const float* __restrict__ g1, const float* __restrict__ be1,
    const float* __restrict__ W1, const float* __restrict__ b1,
    const float* __restrict__ W2, const float* __restrict__ b2,
    const float* __restrict__ g2, const float* __restrict__ be2,
    float* __restrict__ out) {
  const int row = blockIdx.x;
  const int b = row >> 7;
  const int L = threadIdx.x;
  const int jj = L >> 4;
  const int c4 = L & 15;
  const int hh2 = c4 >> 1;      // head of channels 4*c4..4*c4+3
  const size_t kvbase = (size_t)b * NN * ND;

  __shared__ float attn_l[ND];
  __shared__ float n1_l[ND];
  __shared__ float ff_l[2 * ND];

  // phase 2: attn = (S @ V) / rowsum(S)
  float4 an = make_float4(0.f, 0.f, 0.f, 0.f);
  float den = 0.f;
#pragma unroll 8
  for (int t = 0; t < 32; ++t) {
    const int j = t * 4 + jj;
    const float s = bf2f(Sws[((size_t)row * 8 + hh2) * NN + j]);
    const float4 v = *(const float4*)(&V[kvbase + (size_t)j * ND + c4 * 4]);
    an.x = fmaf(s, v.x, an.x);
    an.y = fmaf(s, v.y, an.y);
    an.z = fmaf(s, v.z, an.z);
    an.w = fmaf(s, v.w, an.w);
    den += s;
  }
  an = xor_add4(an, 16); an = xor_add4(an, 32);
  den += __shfl_xor(den, 16, 64); den += __shfl_xor(den, 32, 64);
  const float rden = 1.f / fmaxf(den, 1e-6f);
  if (L < 16)
    *(float4*)(&attn_l[c4 * 4]) =
        make_float4(an.x * rden, an.y * rden, an.z * rden, an.w * rden);
  __builtin_amdgcn_wave_barrier();

  // phase 3: O-proj + residual + LN1
  float4 o4 = make_float4(0.f, 0.f, 0.f, 0.f);
#pragma unroll 4
  for (int t = 0; t < 16; ++t) {
    const int d = t * 4 + jj;
    const float a = attn_l[d];
    const float4 wv = *(const float4*)(&Wo[d * ND + c4 * 4]);
    o4.x = fmaf(a, wv.x, o4.x);
    o4.y = fmaf(a, wv.y, o4.y);
    o4.z = fmaf(a, wv.z, o4.z);
    o4.w = fmaf(a, wv.w, o4.w);
  }
  o4 = xor_add4(o4, 16); o4 = xor_add4(o4, 32);
  const float4 bo4 = *(const float4*)(&bo[c4 * 4]);
  const float4 h4 = *(const float4*)(&h[(size_t)row * ND + c4 * 4]);
  float4 h1;
  h1.x = h4.x + bo4.x + o4.x;
  h1.y = h4.y + bo4.y + o4.y;
  h1.z = h4.z + bo4.z + o4.z;
  h1.w = h4.w + bo4.w + o4.w;
  const float m1 = wsum64(h1.x + h1.y + h1.z + h1.w) * (1.f / 256.f);
  float4 df;
  df.x = h1.x - m1; df.y = h1.y - m1; df.z = h1.z - m1; df.w = h1.w - m1;
  const float v1 =
      wsum64(df.x * df.x + df.y * df.y + df.z * df.z + df.w * df.w) * (1.f / 256.f);
  const float r1 = rsqrtf(v1 + 1e-5f);
  const float4 g14 = *(const float4*)(&g1[c4 * 4]);
  const float4 be14 = *(const float4*)(&be1[c4 * 4]);
  float4 n14;
  n14.x = df.x * r1 * g14.x + be14.x;
  n14.y = df.y * r1 * g14.y + be14.y;
  n14.z = df.z * r1 * g14.z + be14.z;
  n14.w = df.w * r1 * g14.w + be14.w;
  if (L < 16) *(float4*)(&n1_l[c4 * 4]) = n14;
  __builtin_amdgcn_wave_barrier();

  // phase 4: FFN1 + ReLU
  const int dd2 = L >> 5;
  const int c5 = L & 31;
  float4 f4 = make_float4(0.f, 0.f, 0.f, 0.f);
#pragma unroll 8
  for (int t = 0; t < 32; ++t) {
    const int d = t * 2 + dd2;
    const float nv = n1_l[d];
    const float4 wv = *(const float4*)(&W1[d * 128 + c5 * 4]);
    f4.x = fmaf(nv, wv.x, f4.x);
    f4.y = fmaf(nv, wv.y, f4.y);
    f4.z = fmaf(nv, wv.z, f4.z);
    f4.w = fmaf(nv, wv.w, f4.w);
  }
  f4 = xor_add4(f4, 32);
  const float4 b14 = *(const float4*)(&b1[c5 * 4]);
  if (L < 32)
    *(float4*)(&ff_l[c5 * 4]) =
        make_float4(fmaxf(f4.x + b14.x, 0.f), fmaxf(f4.y + b14.y, 0.f),
                    fmaxf(f4.z + b14.z, 0.f), fmaxf(f4.w + b14.w, 0.f));
  __builtin_amdgcn_wave_barrier();

  // phase 5: FFN2 + residual + LN2
  float4 q4 = make_float4(0.f, 0.f, 0.f, 0.f);
#pragma unroll 8
  for (int t = 0; t < 32; ++t) {
    const int u = t * 4 + jj;
    const float fv = ff_l[u];
    const float4 wv = *(const float4*)(&W2[u * ND + c4 * 4]);
    q4.x = fmaf(fv, wv.x, q4.x);
    q4.y = fmaf(fv, wv.y, q4.y);
    q4.z = fmaf(fv, wv.z, q4.z);
    q4.w = fmaf(fv, wv.w, q4.w);
  }
  q4 = xor_add4(q4, 16); q4 = xor_add4(q4, 32);
  const float4 b24 = *(const float4*)(&b2[c4 * 4]);
  float4 x4;
  x4.x = n14.x + b24.x + q4.x;
  x4.y = n14.y + b24.y + q4.y;
  x4.z = n14.z + b24.z + q4.z;
  x4.w = n14.w + b24.w + q4.w;
  const float m2 = wsum64(x4.x + x4.y + x4.z + x4.w) * (1.f / 256.f);
  float4 d2;
  d2.x = x4.x - m2; d2.y = x4.y - m2; d2.z = x4.z - m2; d2.w = x4.w - m2;
  const float v2 =
      wsum64(d2.x * d2.x + d2.y * d2.y + d2.z * d2.z + d2.w * d2.w) * (1.f / 256.f);
  const float r2 = rsqrtf(v2 + 1e-5f);
  const float4 g24 = *(const float4*)(&g2[c4 * 4]);
  const float4 be24 = *(const float4*)(&be2[c4 * 4]);
  if (L < 16)
    *(float4*)(&out[(size_t)row * ND + c4 * 4]) =
        make_float4(d2.x * r2 * g24.x + be24.x, d2.y * r2 * g24.y + be24.y,
                    d2.z * r2 * g24.z + be24.z, d2.w * r2 * g24.w + be24.w);
}

extern "C" void kernel_launch(void* const* d_in, const int* in_sizes, int n_in,
                              void* d_out, int out_size, void* d_ws, size_t ws_size,
                              hipStream_t stream) {
  const float* h   = (const float*)d_in[0];
  const float* e   = (const float*)d_in[2];
  const float* kRW = (const float*)d_in[3];
  const float* Wq  = (const float*)d_in[4];
  const float* Wk  = (const float*)d_in[5];
  const float* We  = (const float*)d_in[6];
  const float* Wv  = (const float*)d_in[7];
  const float* Wo  = (const float*)d_in[8];
  const float* bo  = (const float*)d_in[9];
  const float* g1  = (const float*)d_in[10];
  const float* be1 = (const float*)d_in[11];
  const float* W1  = (const float*)d_in[12];
  const float* b1  = (const float*)d_in[13];
  const float* W2  = (const float*)d_in[14];
  const float* b2  = (const float*)d_in[15];
  const float* g2  = (const float*)d_in[16];
  const float* be2 = (const float*)d_in[17];
  float* out = (float*)d_out;

  float* Q = (float*)d_ws;
  float* K = Q + (size_t)NB * NN * ND;
  float* V = K + (size_t)NB * NN * ND;
  unsigned short* WeT = (unsigned short*)(V + (size_t)NB * NN * ND);
  unsigned short* Sws = WeT + (size_t)ND * ND;   // [4096][8][128] bf16 = 8 MB

  qkv_kernel<<<NB * NN + 1, 64, 0, stream>>>(h, Wq, Wk, Wv, We, Q, K, V, WeT);
  score_kernel<<<NB * NN / G, 256, 0, stream>>>(e, kRW, Q, K, WeT, Sws);
  tail_kernel<<<NB * NN, 64, 0, stream>>>(h, Sws, V, Wo, bo, g1, be1,
                                          W1, b1, W2, b2, g2, be2, out);
}